// Round 1
// 1048.922 us; speedup vs baseline: 1.0109x; 1.0109x over previous
//
#include <hip/hip_runtime.h>

#define CLS 10000
#define BATCH 8192
#define NGRAD 100000000LL  // CLS*CLS

// Native clang vector so __builtin_nontemporal_* accepts it.
typedef float v4f __attribute__((ext_vector_type(4)));

#define ROW_BLOCKS BATCH                       // 8192 rowstats blocks
#define N4 ((NGRAD - 4) / 4)                   // 24999999 aligned float4 stores
#define COPY_PER_THREAD 4                      // 64 B per thread per role-pass
#define COPY_CHUNK (256 * COPY_PER_THREAD)     // float4s per copy block
#define COPY_BLOCKS ((int)((N4 + COPY_CHUNK - 1) / COPY_CHUNK))  // 24415

// Combine two online-softmax partial states (m = running max, s = sum of exp(v - m)).
__device__ __forceinline__ void combine_ms(float& m, float& s, float om, float os) {
  float nm = fmaxf(m, om);
  s = s * __expf(m - nm) + os * __expf(om - nm);
  m = nm;
}

// ONE dispatch, three block roles:
//   blk <  8192            : per-row online softmax + argmax + dot (row b = blk)
//   blk == 8192            : count -> out_count copy + misalignment edge elements
//   blk >  8192            : grad_state -> out+1 copy, nontemporal, float4-aligned stores
// The two big roles are independent BW-bound streams; fusing them lets the CUs
// co-schedule them and removes two graph-node gaps.
__global__ __launch_bounds__(256) void fused_main(
    const float* __restrict__ x, const int* __restrict__ target,
    const float* __restrict__ matrix, const float* __restrict__ grad_state,
    const float* __restrict__ count, float* __restrict__ out,
    float* __restrict__ row_loss, float* __restrict__ row_logZ,
    int* __restrict__ row_correct)
{
  int blk = blockIdx.x;

  if (blk == ROW_BLOCKS) {
    // count copy (out_count = out + 1 + NGRAD is 4B-aligned only -> scalar)
    float* out_count = out + 1 + NGRAD;
    for (int c = threadIdx.x; c < CLS; c += 256) out_count[c] = count[c];
    if (threadIdx.x == 0) {
      // edge elements around the aligned-float4 main body
      out[1] = grad_state[0];
      out[2] = grad_state[1];
      out[3] = grad_state[2];
      out[NGRAD] = grad_state[NGRAD - 1];
    }
    return;
  }

  if (blk > ROW_BLOCKS) {
    // grad copy: src read once, dst written once -> nontemporal on both sides
    // so the 800 MB stream does not evict matrix rows (which have target-dup reuse)
    // from L2/LLC. out+4 is 16B aligned; body k covers out[4+4k .. 7+4k] = src[3+4k .. 6+4k].
    long long base = (long long)(blk - (ROW_BLOCKS + 1)) * COPY_CHUNK + threadIdx.x;
    const float* src = grad_state + 3;
    v4f* dst = (v4f*)(out + 4);
#pragma unroll
    for (int j = 0; j < COPY_PER_THREAD; ++j) {
      long long k = base + (long long)j * 256;
      if (k < N4) {
        const float* s = src + 4 * k;  // 4B-aligned only -> scalar loads
        v4f v;
        v[0] = __builtin_nontemporal_load(s + 0);
        v[1] = __builtin_nontemporal_load(s + 1);
        v[2] = __builtin_nontemporal_load(s + 2);
        v[3] = __builtin_nontemporal_load(s + 3);
        __builtin_nontemporal_store(v, dst + k);
      }
    }
    return;
  }

  // ---- rowstats: one block per batch row ----
  int b = blk;
  int t = target[b];
  const v4f* xr = (const v4f*)(x + (size_t)b * CLS);       // 16B aligned (10000%4==0)
  const float4* mr = (const float4*)(matrix + (size_t)t * CLS);

  float m = -3.4e38f, s = 0.f, dot = 0.f;
  float bestv = -3.4e38f;
  int besti = 0x7fffffff;

  for (int i = threadIdx.x; i < CLS / 4; i += 256) {
    v4f xv = __builtin_nontemporal_load(xr + i);  // x is read-once: keep out of LLC
    float4 mv = mr[i];                            // matrix rows: cached (dup-target reuse)
    dot += xv[0] * mv.x;
    dot += xv[1] * mv.y;
    dot += xv[2] * mv.z;
    dot += xv[3] * mv.w;
    float vals[4] = {xv[0], xv[1], xv[2], xv[3]};
#pragma unroll
    for (int j = 0; j < 4; ++j) {
      float v = vals[j];
      int idx = 4 * i + j;
      // first-occurrence argmax semantics: strict >, ties -> lower index
      if (v > bestv || (v == bestv && idx < besti)) { bestv = v; besti = idx; }
      float nm = fmaxf(m, v);
      s = s * __expf(m - nm) + __expf(v - nm);
      m = nm;
    }
  }

  // wave (64-lane) reduction
#pragma unroll
  for (int off = 32; off > 0; off >>= 1) {
    float om = __shfl_down(m, off);
    float os = __shfl_down(s, off);
    float od = __shfl_down(dot, off);
    float ov = __shfl_down(bestv, off);
    int   oi = __shfl_down(besti, off);
    combine_ms(m, s, om, os);
    dot += od;
    if (ov > bestv || (ov == bestv && oi < besti)) { bestv = ov; besti = oi; }
  }

  // cross-wave (4 waves) reduction via LDS
  __shared__ float sm[4], ss[4], sd[4], sv[4];
  __shared__ int si[4];
  int wave = threadIdx.x >> 6;
  if ((threadIdx.x & 63) == 0) {
    sm[wave] = m; ss[wave] = s; sd[wave] = dot; sv[wave] = bestv; si[wave] = besti;
  }
  __syncthreads();
  if (threadIdx.x == 0) {
    for (int w = 1; w < 4; ++w) {
      combine_ms(m, s, sm[w], ss[w]);
      dot += sd[w];
      if (sv[w] > bestv || (sv[w] == bestv && si[w] < besti)) { bestv = sv[w]; besti = si[w]; }
    }
    float logZ = m + __logf(s);
    row_logZ[b] = logZ;
    row_correct[b] = (besti == t) ? 1 : 0;
    row_loss[b] = logZ - dot;  // softlabel rows sum to 1
  }
}

// ONE epilogue dispatch:
//   block 0       : deterministic mean of row_loss -> out[0]
//   all blocks b  : if pred==target, out_grad[t,:] += softmax(x[b,:]); out_count[t] += 1
// Safe vs kernel A: grad copy and count copy are complete before any atomicAdd here.
__global__ __launch_bounds__(256) void fused_epilogue(
    const float* __restrict__ x, const int* __restrict__ target,
    const float* __restrict__ row_loss, const float* __restrict__ row_logZ,
    const int* __restrict__ row_correct, float* __restrict__ out)
{
  int b = blockIdx.x;

  if (b == 0) {
    float acc = 0.f;
    for (int i = threadIdx.x; i < BATCH; i += 256) acc += row_loss[i];
#pragma unroll
    for (int off = 32; off > 0; off >>= 1) acc += __shfl_down(acc, off);
    __shared__ float sw[4];
    if ((threadIdx.x & 63) == 0) sw[threadIdx.x >> 6] = acc;
    __syncthreads();
    if (threadIdx.x == 0)
      out[0] = (sw[0] + sw[1] + sw[2] + sw[3]) * (1.0f / BATCH);
  }

  if (!row_correct[b]) return;
  int t = target[b];
  float lz = row_logZ[b];
  const float* xr = x + (size_t)b * CLS;
  float* gr = out + 1 + (size_t)t * CLS;
  float* out_count = out + 1 + NGRAD;
  for (int c = threadIdx.x; c < CLS; c += 256)
    atomicAdd(&gr[c], __expf(xr[c] - lz));
  if (threadIdx.x == 0) atomicAdd(&out_count[t], 1.0f);
}

extern "C" void kernel_launch(void* const* d_in, const int* in_sizes, int n_in,
                              void* d_out, int out_size, void* d_ws, size_t ws_size,
                              hipStream_t stream)
{
  const float* x          = (const float*)d_in[0];
  const int*   target     = (const int*)d_in[1];
  const float* matrix     = (const float*)d_in[2];
  const float* grad_state = (const float*)d_in[3];
  const float* count      = (const float*)d_in[4];

  float* out = (float*)d_out;

  float* row_loss    = (float*)d_ws;                 // [BATCH]
  float* row_logZ    = row_loss + BATCH;             // [BATCH]
  int*   row_correct = (int*)(row_logZ + BATCH);     // [BATCH]

  int gridA = ROW_BLOCKS + 1 + COPY_BLOCKS;
  fused_main<<<gridA, 256, 0, stream>>>(x, target, matrix, grad_state, count,
                                        out, row_loss, row_logZ, row_correct);
  fused_epilogue<<<BATCH, 256, 0, stream>>>(x, target, row_loss, row_logZ,
                                            row_correct, out);
}